// Round 8
// baseline (312.783 us; speedup 1.0000x reference)
//
#include <hip/hip_runtime.h>
#include <hip/hip_bf16.h>
#include <hip/hip_cooperative_groups.h>
#include <cstdint>
#include <cstddef>

namespace cg = cooperative_groups;

// Problem constants (L=256, C=20, LC=5120, BATCH=1024)
#define LCN 5120
#define BN  1024
#define CN  20

typedef __attribute__((ext_vector_type(4))) float  floatx4;
typedef __attribute__((ext_vector_type(8))) short  shortx8;
typedef __attribute__((ext_vector_type(8))) unsigned short ushortx8;

static __device__ __forceinline__ unsigned short f2bf(float f) {
    __hip_bfloat16 h = __float2bfloat16(f);
    return *reinterpret_cast<unsigned short*>(&h);
}

static __device__ __forceinline__ void gload_lds16(const void* g, void* l) {
    __builtin_amdgcn_global_load_lds(
        (const __attribute__((address_space(1))) void*)g,
        (__attribute__((address_space(3))) void*)l,
        16, 0, 0);
}

// ---------------------------------------------------------------------------
// FUSED cooperative kernel (grid 256 x 512 = exactly 1 block/CU, co-resident).
//
// Symmetric decomposition: quad[b] = sum_i x[b,i] * sum_j Theta[i,j]*(l_j>l_i)*x[b,j]
// B operand = Theta's own rows (k = j contiguous), mask j >= jmin_i.
//
// PHASE 0 (prep, in-kernel — kills the Tb HBM round-trip across a kernel
// boundary; converted slabs stay in the producing XCD's L2 / die L3):
//   - active block (qc<60, sibling m): converts ITS OWN chunk B-slab portion
//     rows n0+m*64..+63, cols k0..k0+1023 (fp32 -> masked bf16 -> Tb).
//     Same XCD as all 4 consumers of the chunk (bid%8 mapping) -> L2-local.
//   - every block: 4 x-rows -> Xb bf16 + linear term out[b]=th0+thlc.x[b].
//  __threadfence() + grid.sync() = device-scope release/acquire (correct
//  regardless of XCD placement; L2 story is perf-only).
//
// PHASE 1 (quad, R5 body unchanged — best measured): 256x256 tile, BK=32,
// 8 waves (2M x 4N), K-chunk 1024 -> 32 tiles; 4 LDS buffers, stage lead 3,
// counted vmcnt(8) (never 0 until drain), ONE barrier/tile, setprio on MFMA.
// LDS SEG SWIZZLE (0-conflict): seg g of row r at slot (g+(r>>1))&3;
// readers use slot (kq+(row>>1))&3.
// ---------------------------------------------------------------------------
__global__ __launch_bounds__(512, 2) void k_fused(
    const float* __restrict__ x,     // [1024,5120]
    const float* __restrict__ th0,   // [1]
    const float* __restrict__ thlc,  // [5120]
    const float* __restrict__ th,    // [5120,5120] theta_lclc fp32
    unsigned short* __restrict__ Tb, // [5120,5120] bf16 masked theta (ws)
    unsigned short* __restrict__ Xb, // [1024,5120] bf16 x (ws)
    float*          __restrict__ out)// [1024]
{
    const int bid  = blockIdx.x;
    const int xcd  = bid & 7;
    const int slot = bid >> 3;
    const int m    = slot & 3;    // M tile (256 batch rows)
    const int cl   = slot >> 2;
    const int qc   = cl * 8 + xcd;        // chunk ordinal 0..59 (64 padded)
    const bool active = (qc < 60);
    const int tid  = threadIdx.x;

    // chunk ordinal -> (n-tile, k-chunk) over 1024-wide suffix chunks
    int n = 0, cs = 0;
    if (active) {
        int q = qc;
        for (int t = 0; t < 20; ++t) {
            const int lmin = (256 * t) / CN;
            const int c0   = (CN * (lmin + 1)) / 1024;
            const int cnt  = 5 - c0;
            if (q < cnt) { n = t; cs = c0 + q; break; }
            q -= cnt;
        }
    }
    const int b0 = m * 256;
    const int n0 = n * 256;
    const int k0 = cs * 1024;

    __shared__ unsigned short As[4 * 256 * 32];   // 4-buf A (64 KB)
    __shared__ unsigned short Bs[4 * 256 * 32];   // 4-buf B (64 KB)
    __shared__ float partial[256];
    __shared__ float ws8[8];

    // ================= PHASE 0a: convert own B-slab (64 rows x 1024) ======
    if (active) {
        const int rbase = n0 + m * 64;
        const int colb  = (tid & 127) * 8;    // col-seg within chunk
        const int rowo  = tid >> 7;           // 0..3
#pragma unroll 4
        for (int p = 0; p < 16; ++p) {
            const int r    = rbase + p * 4 + rowo;
            const int jmin = (r / CN) * CN + CN;      // keep iff j >= jmin
            const int j0   = k0 + colb;
            const float* src = th + (size_t)r * LCN + j0;
            const floatx4 v0 = *reinterpret_cast<const floatx4*>(src);
            const floatx4 v1 = *reinterpret_cast<const floatx4*>(src + 4);
            ushortx8 o;
#pragma unroll
            for (int e = 0; e < 4; ++e) {
                o[e]     = (j0 + e     >= jmin) ? f2bf(v0[e]) : (unsigned short)0;
                o[4 + e] = (j0 + 4 + e >= jmin) ? f2bf(v1[e]) : (unsigned short)0;
            }
            *reinterpret_cast<ushortx8*>(Tb + (size_t)r * LCN + j0) = o;
        }
    }

    // ================= PHASE 0b: x rows bid*4..+3 (all 256 blocks) ========
    {
        const int xr = (bid << 2) + (tid >> 7);   // 0..1023
        const int t2 = tid & 127;
        const float* xs = x + (size_t)xr * LCN;
        float s = 0.0f;
#pragma unroll
        for (int it = 0; it < 5; ++it) {
            const int k = it * 1024 + t2 * 8;
            const floatx4 a0 = *reinterpret_cast<const floatx4*>(xs + k);
            const floatx4 a1 = *reinterpret_cast<const floatx4*>(xs + k + 4);
            const floatx4 t0 = *reinterpret_cast<const floatx4*>(thlc + k);
            const floatx4 t1 = *reinterpret_cast<const floatx4*>(thlc + k + 4);
            s += a0[0]*t0[0] + a0[1]*t0[1] + a0[2]*t0[2] + a0[3]*t0[3]
               + a1[0]*t1[0] + a1[1]*t1[1] + a1[2]*t1[2] + a1[3]*t1[3];
            ushortx8 o;
#pragma unroll
            for (int e = 0; e < 4; ++e) { o[e] = f2bf(a0[e]); o[4 + e] = f2bf(a1[e]); }
            *reinterpret_cast<ushortx8*>(Xb + (size_t)xr * LCN + k) = o;
        }
#pragma unroll
        for (int off = 32; off > 0; off >>= 1) s += __shfl_down(s, off, 64);
        if ((tid & 63) == 0) ws8[tid >> 6] = s;
        __syncthreads();
        if (t2 == 0) out[xr] = th0[0] + ws8[(tid >> 7) * 2] + ws8[(tid >> 7) * 2 + 1];
    }

    // ================= grid-wide release/acquire ==========================
    __threadfence();
    cg::this_grid().sync();
    if (!active) return;

    // ================= PHASE 1: quad (R5 body) ============================
    const int lane = tid & 63;
    const int w    = tid >> 6;        // wave 0..7
    const int wm   = w & 1;           // M half (128 rows)
    const int wn   = w >> 1;          // N quarter (64 cols)
    const int lrow = lane & 15;
    const int kq   = lane >> 4;       // 0..3

    if (tid < 256) partial[tid] = 0.0f;

    floatx4 acc[8][4];
#pragma unroll
    for (int mt = 0; mt < 8; ++mt)
#pragma unroll
        for (int nt = 0; nt < 4; ++nt) acc[mt][nt] = (floatx4)0.0f;

    int aoff[8], boff[4];
#pragma unroll
    for (int mt = 0; mt < 8; ++mt) {
        const int row = wm * 128 + mt * 16 + lrow;
        aoff[mt] = row * 32 + (((kq + (row >> 1)) & 3) << 3);
    }
#pragma unroll
    for (int nt = 0; nt < 4; ++nt) {
        const int row = wn * 64 + nt * 16 + lrow;
        boff[nt] = row * 32 + (((kq + (row >> 1)) & 3) << 3);
    }

#define STAGE(buf, kc) do {                                                       \
    _Pragma("unroll")                                                             \
    for (int t = 0; t < 2; ++t) {                                                 \
        const int s    = t * 512 + tid;                                           \
        const int row  = s >> 2;                                                  \
        const int gseg = ((s & 3) - (row >> 1)) & 3;                              \
        char* la = (char*)As + (buf) * 16384 + (size_t)(t * 512 + w * 64) * 16;   \
        char* lb = (char*)Bs + (buf) * 16384 + (size_t)(t * 512 + w * 64) * 16;   \
        gload_lds16(Xb + (size_t)(b0 + row) * LCN + (kc) + gseg * 8, la);         \
        gload_lds16(Tb + (size_t)(n0 + row) * LCN + (kc) + gseg * 8, lb);         \
    }                                                                             \
} while (0)

#define BODY(kk, PAR, VM) do {                                                     \
    asm volatile("s_waitcnt vmcnt(" #VM ")" ::: "memory");                         \
    __builtin_amdgcn_s_barrier();                                                  \
    if ((kk) + 3 < 32) STAGE(((PAR) + 3) & 3, k0 + ((kk) + 3) * 32);               \
    shortx8 bf4[4], af8[8];                                                        \
    _Pragma("unroll")                                                              \
    for (int nt = 0; nt < 4; ++nt)                                                 \
        bf4[nt] = *reinterpret_cast<const shortx8*>(Bs + (PAR) * 8192 + boff[nt]); \
    _Pragma("unroll")                                                              \
    for (int mt = 0; mt < 8; ++mt)                                                 \
        af8[mt] = *reinterpret_cast<const shortx8*>(As + (PAR) * 8192 + aoff[mt]); \
    __builtin_amdgcn_s_setprio(1);                                                 \
    _Pragma("unroll")                                                              \
    for (int mt = 0; mt < 8; ++mt)                                                 \
        _Pragma("unroll")                                                          \
        for (int nt = 0; nt < 4; ++nt)                                             \
            acc[mt][nt] = __builtin_amdgcn_mfma_f32_16x16x32_bf16(af8[mt], bf4[nt], acc[mt][nt], 0, 0, 0); \
    __builtin_amdgcn_s_setprio(0);                                                 \
} while (0)

    STAGE(0, k0);
    STAGE(1, k0 + 32);
    STAGE(2, k0 + 64);

    for (int kk = 0; kk < 28; kk += 4) {
        BODY(kk + 0, 0, 8);
        BODY(kk + 1, 1, 8);
        BODY(kk + 2, 2, 8);
        BODY(kk + 3, 3, 8);
    }
    BODY(28, 0, 8);
    BODY(29, 1, 8);
    BODY(30, 2, 4);
    BODY(31, 3, 0);
#undef BODY
#undef STAGE

    // Epilogue: C/D layout col = lane&15 (i), row = (lane>>4)*4 + reg (b)
#pragma unroll
    for (int mt = 0; mt < 8; ++mt) {
#pragma unroll
        for (int r = 0; r < 4; ++r) {
            const int b = b0 + wm * 128 + mt * 16 + kq * 4 + r;
            float s = 0.0f;
#pragma unroll
            for (int nt = 0; nt < 4; ++nt) {
                const int i = n0 + wn * 64 + nt * 16 + lrow;
                const __hip_bfloat16 hv = *reinterpret_cast<const __hip_bfloat16*>(&Xb[(size_t)b * LCN + i]);
                s += acc[mt][nt][r] * __bfloat162float(hv);
            }
            s += __shfl_xor(s, 1, 64);
            s += __shfl_xor(s, 2, 64);
            s += __shfl_xor(s, 4, 64);
            s += __shfl_xor(s, 8, 64);
            if (lrow == 0) atomicAdd(&partial[b - b0], s);
        }
    }
    __syncthreads();
    if (tid < 256) atomicAdd(&out[b0 + tid], partial[tid]);
}

// ---------------------------------------------------------------------------
extern "C" void kernel_launch(void* const* d_in, const int* in_sizes, int n_in,
                              void* d_out, int out_size, void* d_ws, size_t ws_size,
                              hipStream_t stream) {
    const float* x      = (const float*)d_in[0];  // [1024, 5120]
    const float* th0    = (const float*)d_in[1];  // [1]
    const float* thlc   = (const float*)d_in[2];  // [5120]
    const float* thlclc = (const float*)d_in[3];  // [5120, 5120]
    float* out = (float*)d_out;                   // [1024]

    // ws layout: Tb (bf16 5120x5120 = 52.4 MB) | Xb (bf16 1024x5120 = 10.5 MB)
    unsigned short* Tb = (unsigned short*)d_ws;
    unsigned short* Xb = (unsigned short*)((char*)d_ws + (size_t)LCN * LCN * 2);

    void* args[] = { (void*)&x, (void*)&th0, (void*)&thlc, (void*)&thlclc,
                     (void*)&Tb, (void*)&Xb, (void*)&out };
    // 256 blocks x 512 threads, 1 block/CU (129.3 KB LDS) -> all co-resident
    hipLaunchCooperativeKernel((const void*)k_fused, dim3(256), dim3(512),
                               args, 0, stream);
}